// Round 6
// baseline (654.247 us; speedup 1.0000x reference)
//
#include <hip/hip_runtime.h>

// HydraBackbonePlus: 10 dilations x {X, diffX} x 32 groups, 9-tap grouped dilated
// conv (8 out-ch per group), per-position argmax/argmin over 8 channels,
// histogram-reduced to (32, 1280, 8) with relu.
//
// R16 vs R15 (452 us: f16 tile halved LDS traffic+conflicts, raised occupancy,
// yet SLOWER -> LDS bw/conflicts/occupancy are NOT the limiter; reverted).
// Base = R12 (421 us, f32 tile). New theory: the Smx per-position LDS RMW is a
// serialized may-alias chain (ds_read p+1 can't hoist above ds_write p; ~120cy
// LDS round-trip x8 per inner iter > the 575cy compute body) -> half the wall
// is this stall (wall 421 vs real VALU ~188 us after 2x wave64 counter inflation).
// R16: cmx accumulation moved to 8 NAMED REGISTERS per thread.
//  - bin select: integer tag compare (mxb&7)==k -> v_cmp_eq_u32+cndmask+add
//    (exact single match; +21 VALU/pos, removes the LDS chain entirely)
//  - Smx LDS array deleted: block LDS 39424 -> ~31232 B -> 5 blocks/CU
//  - flush: shfl_xor butterfly over the 8 s-lanes (registers only, no barrier)
// Kept: 8-wide st-loop, v_max3/v_min3, packed-u64 cmn, f32 LDS tile (R12 geom).

typedef __fp16 h2_t __attribute__((ext_vector_type(2)));

#define NB    32
#define CIN   12
#define SEQ   8192
#define NG    32
#define CPER  6
#define OUTCH 1280
#define XS_FLOATS 7728   // 12 * 644 = max over DI of CIN*CS
#define GRID  10240      // 20 (di,j) * 32 b * 16 chunks

#define MAX3F(a, b, c) ({ float _r; asm("v_max3_f32 %0, %1, %2, %3" \
    : "=v"(_r) : "v"(a), "v"(b), "v"(c)); _r; })
#define MIN3F(a, b, c) ({ float _r; asm("v_min3_f32 %0, %1, %2, %3" \
    : "=v"(_r) : "v"(a), "v"(b), "v"(c)); _r; })

template <int DI>
__device__ __forceinline__ void hydra_body(
    const float* __restrict__ X, const float* __restrict__ W,
    const int* __restrict__ I, float* __restrict__ out,
    float* Xs, int j, int b, int chunk) {

  constexpr int d   = 1 << DI;
  constexpr int R   = (d < 16) ? d : 16;       // residues per tile row-set
  constexpr int rb  = (DI < 4) ? DI : 4;       // log2(R)
  constexpr int Mm  = SEQ / d;                 // m-extent of a residue
  constexpr int TMc = 512 / R;
  constexpr int TM  = (TMc < Mm) ? TMc : Mm;   // m per tile (DI=9 -> 16)
  constexpr int MC  = Mm / TM;
  constexpr int RC  = d / R;
  constexpr int NR  = (RC * MC) / 16;          // chunks per block: 1 (DI<9), 2 (DI=9)
  constexpr int SR  = TM + 8;                  // row stride (exact halo)
  constexpr int CS  = R * SR + 4;              // channel stride
  constexpr int CL  = (R >= 8) ? TM : (TM * R / 8);  // m per thread per rep
  constexpr int REP = (R == 16) ? 2 : 1;

  const int L = SEQ - j;
  const int tid = threadIdx.x;
  const int g = tid >> 3, s = tid & 7;

  // weights: 8 out-ch x 9 taps -> 4 half2 + 1 f32 tail per channel (40 regs)
  h2_t Wp[8][4];
  float Wt[8];
  {
    const float* wp = W + (size_t)((DI * 2 + j) * 256 + g * 8) * 9;
#pragma unroll
    for (int k = 0; k < 8; ++k) {
#pragma unroll
      for (int t = 0; t < 4; ++t)
        Wp[k][t] = __builtin_amdgcn_cvt_pkrtz(wp[k * 9 + 2 * t], wp[k * 9 + 2 * t + 1]);
      Wt[k] = wp[k * 9 + 8];
    }
  }
  const float* base[CPER];
  {
    const int* ip = I + ((DI * 2 + j) * NG + g) * CPER;
#pragma unroll
    for (int i = 0; i < CPER; ++i) base[i] = Xs + ip[i] * CS;
  }

  // cmx: 8 per-thread register accumulators (no LDS, no RMW chain)
  float acc[8];
#pragma unroll
  for (int k = 0; k < 8; ++k) acc[k] = 0.f;

  // cmn: 8 bins as packed u8 lanes of one u64 (counts <= 64/thread)
  unsigned long long cmnp = 0ull;

  for (int n = 0; n < NR; ++n) {
    const int cidx = chunk + 16 * n;
    const int rc = cidx & (RC - 1);
    const int mc = cidx / RC;
    const int r0 = rc * R;
    const int m0 = mc * TM;

    if (NR > 1 && n) __syncthreads();

    // ---- stage 12-channel tile into LDS, zero-padded; guards hoisted ----
    {
      const float* xb0 = X + (size_t)b * CIN * SEQ;
      if (j == 0) {
        for (int f = tid; f < R * SR; f += 256) {
          int rr = f & (R - 1), mm = f >> rb, mp = m0 + mm - 4;
          int pos = r0 + rr + mp * d;
          bool ok = (mp >= 0) && (pos < L);
          int lo = rr * SR + mm;
          const float* xp = xb0 + pos;
#pragma unroll
          for (int ch = 0; ch < CIN; ++ch) {
            Xs[ch * CS + lo] = ok ? xp[0] : 0.f;
            xp += SEQ;
          }
        }
      } else {
        for (int f = tid; f < R * SR; f += 256) {
          int rr = f & (R - 1), mm = f >> rb, mp = m0 + mm - 4;
          int pos = r0 + rr + mp * d;
          bool ok = (mp >= 0) && (pos < L);
          int lo = rr * SR + mm;
          const float* xp = xb0 + pos;
#pragma unroll
          for (int ch = 0; ch < CIN; ++ch) {
            Xs[ch * CS + lo] = ok ? (xp[1] - xp[0]) : 0.f;
            xp += SEQ;
          }
        }
      }
    }
    __syncthreads();

    // ---- compute: sliding window, dot2 conv, mantissa-tag binning ----
#pragma unroll
    for (int rep = 0; rep < REP; ++rep) {
      int rr = (R == 16) ? (s + (rep << 3)) : (s & (R - 1));
      int mst = (R >= 8) ? 0 : ((s >> rb) * CL);
      int rowoff = rr * SR + mst;

      auto ldsum = [&](int idx) {
        float4 r = *reinterpret_cast<const float4*>(base[0] + idx);
#pragma unroll
        for (int i = 1; i < CPER; ++i) {
          float4 t = *reinterpret_cast<const float4*>(base[i] + idx);
          r.x += t.x; r.y += t.y; r.z += t.z; r.w += t.w;
        }
        return r;
      };

      float4 w0 = ldsum(rowoff);
      float4 w1 = ldsum(rowoff + 4);
#pragma unroll 1
      for (int st = 0; st < CL; st += 8) {
        float4 w2 = ldsum(rowoff + st + 8);
        float4 w3 = ldsum(rowoff + st + 12);
        float xv[16] = {w0.x, w0.y, w0.z, w0.w,
                        w1.x, w1.y, w1.z, w1.w,
                        w2.x, w2.y, w2.z, w2.w,
                        w3.x, w3.y, w3.z, w3.w};
        // even- and odd-aligned f16 pair windows covering xv[0..15]
        h2_t E[8], O[7];
#pragma unroll
        for (int i = 0; i < 8; ++i)
          E[i] = __builtin_amdgcn_cvt_pkrtz(xv[2 * i], xv[2 * i + 1]);
#pragma unroll
        for (int i = 0; i < 7; ++i)
          O[i] = __builtin_amdgcn_cvt_pkrtz(xv[2 * i + 1], xv[2 * i + 2]);
#pragma unroll
        for (int p = 0; p < 8; ++p) {
          const h2_t* P = (p & 1) ? (O + (p >> 1)) : (E + (p >> 1));
          float tail = xv[8 + p];
          // conv + mantissa-tag: zp[k] = (bits(z) & ~7) | k  (v_and_or_b32)
          float zp[8];
#pragma unroll
          for (int k = 0; k < 8; ++k) {
            float a0 = Wt[k] * tail;
            a0 = __builtin_amdgcn_fdot2(Wp[k][3], P[3], a0, false);
            a0 = __builtin_amdgcn_fdot2(Wp[k][2], P[2], a0, false);
            a0 = __builtin_amdgcn_fdot2(Wp[k][1], P[1], a0, false);
            a0 = __builtin_amdgcn_fdot2(Wp[k][0], P[0], a0, false);
            zp[k] = __uint_as_float((__float_as_uint(a0) & 0xFFFFFFF8u) | (unsigned)k);
          }
          // max/min trees via v_max3/v_min3: 4+4 ops (was 7+7)
          float t1 = MAX3F(zp[0], zp[1], zp[2]);
          float t2 = MAX3F(zp[3], zp[4], zp[5]);
          float t3 = MAX3F(zp[6], zp[7], t1);
          float mxp = fmaxf(t2, t3);
          float u1 = MIN3F(zp[0], zp[1], zp[2]);
          float u2 = MIN3F(zp[3], zp[4], zp[5]);
          float u3 = MIN3F(zp[6], zp[7], u1);
          float mnp = fminf(u2, u3);
          // cmx: branchless register binning via exact integer tag compare
          // (v_cmp_eq_u32 + v_cndmask + v_add per bin; no LDS, no alias chain)
          unsigned t = __float_as_uint(mxp) & 7u;
#pragma unroll
          for (int k = 0; k < 8; ++k)
            acc[k] += (t == (unsigned)k) ? mxp : 0.f;
          // cmn: packed-byte histogram in a u64 register
          unsigned mnb = __float_as_uint(mnp);
          cmnp += 1ull << ((mnb & 7u) << 3);
        }
        w0 = w2; w1 = w3;
      }
    }
  }

  // ---- flush (registers only, no barrier needed) ----
  {
    int cbase = (DI * 2 + j) * 64;
    // cmx: butterfly-sum each bin over the 8 s-lanes; lane s commits bin s
#pragma unroll
    for (int k = 0; k < 8; ++k) {
#pragma unroll
      for (int off = 1; off < 8; off <<= 1)
        acc[k] += __shfl_xor(acc[k], off);
    }
    float vm = acc[0];
#pragma unroll
    for (int k = 1; k < 8; ++k) vm = (s == k) ? acc[k] : vm;
    atomicAdd(out + ((size_t)b * OUTCH + cbase + g) * 8 + s, vm);

    // cmn: unpack bytes, butterfly over the 8 s-lanes, lane s commits bin s
    int cnts[8];
#pragma unroll
    for (int k = 0; k < 8; ++k) cnts[k] = (int)((cmnp >> (k * 8)) & 0xFFull);
#pragma unroll
    for (int k = 0; k < 8; ++k) {
#pragma unroll
      for (int off = 1; off < 8; off <<= 1)
        cnts[k] += __shfl_xor(cnts[k], off);
    }
    int vn = cnts[0];
#pragma unroll
    for (int k = 1; k < 8; ++k) vn = (s == k) ? cnts[k] : vn;
    atomicAdd(out + ((size_t)b * OUTCH + cbase + 32 + g) * 8 + s, (float)vn);
  }
}

__global__ __launch_bounds__(256, 5) void hydra_fused(
    const float* __restrict__ X, const float* __restrict__ W,
    const int* __restrict__ I, float* __restrict__ out) {
  __shared__ float Xs[XS_FLOATS];
  int u = blockIdx.x;
  int dj = u % 20;            // consecutive blocks interleave (di,j)
  int rest = u / 20;
  int b = rest & 31;
  int chunk = rest >> 5;
  int j = dj & 1;
  switch (dj >> 1) {
    case 0: hydra_body<0>(X, W, I, out, Xs, j, b, chunk); break;
    case 1: hydra_body<1>(X, W, I, out, Xs, j, b, chunk); break;
    case 2: hydra_body<2>(X, W, I, out, Xs, j, b, chunk); break;
    case 3: hydra_body<3>(X, W, I, out, Xs, j, b, chunk); break;
    case 4: hydra_body<4>(X, W, I, out, Xs, j, b, chunk); break;
    case 5: hydra_body<5>(X, W, I, out, Xs, j, b, chunk); break;
    case 6: hydra_body<6>(X, W, I, out, Xs, j, b, chunk); break;
    case 7: hydra_body<7>(X, W, I, out, Xs, j, b, chunk); break;
    case 8: hydra_body<8>(X, W, I, out, Xs, j, b, chunk); break;
    case 9: hydra_body<9>(X, W, I, out, Xs, j, b, chunk); break;
  }
}

__global__ void hydra_relu(float* __restrict__ out, int n) {
  int i = blockIdx.x * 256 + threadIdx.x;
  if (i < n) out[i] = fmaxf(out[i], 0.f);
}

extern "C" void kernel_launch(void* const* d_in, const int* in_sizes, int n_in,
                              void* d_out, int out_size, void* d_ws, size_t ws_size,
                              hipStream_t stream) {
  const float* X = (const float*)d_in[0];
  const float* W = (const float*)d_in[1];
  const int*   I = (const int*)d_in[2];
  float* out = (float*)d_out;

  (void)hipMemsetAsync(d_out, 0, (size_t)out_size * sizeof(float), stream);
  hydra_fused<<<GRID, 256, 0, stream>>>(X, W, I, out);
  hydra_relu<<<(out_size + 255) / 256, 256, 0, stream>>>(out, out_size);
}

// Round 7
// 501.923 us; speedup vs baseline: 1.3035x; 1.3035x over previous
//
#include <hip/hip_runtime.h>

// HydraBackbonePlus: 10 dilations x {X, diffX} x 32 groups, 9-tap grouped dilated
// conv (8 out-ch per group), per-position argmax/argmin over 8 channels,
// histogram-reduced to (32, 1280, 8) with relu.
//
// R17 vs R16 (654 us FAIL: launch_bounds(256,5) squeezed allocator to 48 VGPR
// -> ~100 dwords/thread scratch spill -> 2.1 GB HBM traffic, wall == scratch
// roofline. Design untested, bounds poisoned it.):
//  - ONLY change: __launch_bounds__(256,3) (R12's proven spill-free bound).
//    Expected ~80 VGPR live, no spill; occupancy min(LDS 5, VGPR 6) = 5 blk/CU.
// Design (from R16): cmx accumulation in 8 NAMED REGISTERS per thread.
//  - bin select: integer tag compare (mxb&7)==k -> v_cmp_eq_u32+cndmask+add
//    (exact single match; removes the per-position Smx LDS RMW alias chain)
//  - no Smx LDS: block LDS 31232 B; flush = shfl_xor butterfly (regs only)
// Kept: 8-wide st-loop, v_max3/v_min3, packed-u64 cmn, f32 LDS tile (R12 geom).

typedef __fp16 h2_t __attribute__((ext_vector_type(2)));

#define NB    32
#define CIN   12
#define SEQ   8192
#define NG    32
#define CPER  6
#define OUTCH 1280
#define XS_FLOATS 7728   // 12 * 644 = max over DI of CIN*CS
#define GRID  10240      // 20 (di,j) * 32 b * 16 chunks

#define MAX3F(a, b, c) ({ float _r; asm("v_max3_f32 %0, %1, %2, %3" \
    : "=v"(_r) : "v"(a), "v"(b), "v"(c)); _r; })
#define MIN3F(a, b, c) ({ float _r; asm("v_min3_f32 %0, %1, %2, %3" \
    : "=v"(_r) : "v"(a), "v"(b), "v"(c)); _r; })

template <int DI>
__device__ __forceinline__ void hydra_body(
    const float* __restrict__ X, const float* __restrict__ W,
    const int* __restrict__ I, float* __restrict__ out,
    float* Xs, int j, int b, int chunk) {

  constexpr int d   = 1 << DI;
  constexpr int R   = (d < 16) ? d : 16;       // residues per tile row-set
  constexpr int rb  = (DI < 4) ? DI : 4;       // log2(R)
  constexpr int Mm  = SEQ / d;                 // m-extent of a residue
  constexpr int TMc = 512 / R;
  constexpr int TM  = (TMc < Mm) ? TMc : Mm;   // m per tile (DI=9 -> 16)
  constexpr int MC  = Mm / TM;
  constexpr int RC  = d / R;
  constexpr int NR  = (RC * MC) / 16;          // chunks per block: 1 (DI<9), 2 (DI=9)
  constexpr int SR  = TM + 8;                  // row stride (exact halo)
  constexpr int CS  = R * SR + 4;              // channel stride
  constexpr int CL  = (R >= 8) ? TM : (TM * R / 8);  // m per thread per rep
  constexpr int REP = (R == 16) ? 2 : 1;

  const int L = SEQ - j;
  const int tid = threadIdx.x;
  const int g = tid >> 3, s = tid & 7;

  // weights: 8 out-ch x 9 taps -> 4 half2 + 1 f32 tail per channel (40 regs)
  h2_t Wp[8][4];
  float Wt[8];
  {
    const float* wp = W + (size_t)((DI * 2 + j) * 256 + g * 8) * 9;
#pragma unroll
    for (int k = 0; k < 8; ++k) {
#pragma unroll
      for (int t = 0; t < 4; ++t)
        Wp[k][t] = __builtin_amdgcn_cvt_pkrtz(wp[k * 9 + 2 * t], wp[k * 9 + 2 * t + 1]);
      Wt[k] = wp[k * 9 + 8];
    }
  }
  const float* base[CPER];
  {
    const int* ip = I + ((DI * 2 + j) * NG + g) * CPER;
#pragma unroll
    for (int i = 0; i < CPER; ++i) base[i] = Xs + ip[i] * CS;
  }

  // cmx: 8 per-thread register accumulators (no LDS, no RMW chain)
  float acc[8];
#pragma unroll
  for (int k = 0; k < 8; ++k) acc[k] = 0.f;

  // cmn: 8 bins as packed u8 lanes of one u64 (counts <= 64/thread)
  unsigned long long cmnp = 0ull;

  for (int n = 0; n < NR; ++n) {
    const int cidx = chunk + 16 * n;
    const int rc = cidx & (RC - 1);
    const int mc = cidx / RC;
    const int r0 = rc * R;
    const int m0 = mc * TM;

    if (NR > 1 && n) __syncthreads();

    // ---- stage 12-channel tile into LDS, zero-padded; guards hoisted ----
    {
      const float* xb0 = X + (size_t)b * CIN * SEQ;
      if (j == 0) {
        for (int f = tid; f < R * SR; f += 256) {
          int rr = f & (R - 1), mm = f >> rb, mp = m0 + mm - 4;
          int pos = r0 + rr + mp * d;
          bool ok = (mp >= 0) && (pos < L);
          int lo = rr * SR + mm;
          const float* xp = xb0 + pos;
#pragma unroll
          for (int ch = 0; ch < CIN; ++ch) {
            Xs[ch * CS + lo] = ok ? xp[0] : 0.f;
            xp += SEQ;
          }
        }
      } else {
        for (int f = tid; f < R * SR; f += 256) {
          int rr = f & (R - 1), mm = f >> rb, mp = m0 + mm - 4;
          int pos = r0 + rr + mp * d;
          bool ok = (mp >= 0) && (pos < L);
          int lo = rr * SR + mm;
          const float* xp = xb0 + pos;
#pragma unroll
          for (int ch = 0; ch < CIN; ++ch) {
            Xs[ch * CS + lo] = ok ? (xp[1] - xp[0]) : 0.f;
            xp += SEQ;
          }
        }
      }
    }
    __syncthreads();

    // ---- compute: sliding window, dot2 conv, mantissa-tag binning ----
#pragma unroll
    for (int rep = 0; rep < REP; ++rep) {
      int rr = (R == 16) ? (s + (rep << 3)) : (s & (R - 1));
      int mst = (R >= 8) ? 0 : ((s >> rb) * CL);
      int rowoff = rr * SR + mst;

      auto ldsum = [&](int idx) {
        float4 r = *reinterpret_cast<const float4*>(base[0] + idx);
#pragma unroll
        for (int i = 1; i < CPER; ++i) {
          float4 t = *reinterpret_cast<const float4*>(base[i] + idx);
          r.x += t.x; r.y += t.y; r.z += t.z; r.w += t.w;
        }
        return r;
      };

      float4 w0 = ldsum(rowoff);
      float4 w1 = ldsum(rowoff + 4);
#pragma unroll 1
      for (int st = 0; st < CL; st += 8) {
        float4 w2 = ldsum(rowoff + st + 8);
        float4 w3 = ldsum(rowoff + st + 12);
        float xv[16] = {w0.x, w0.y, w0.z, w0.w,
                        w1.x, w1.y, w1.z, w1.w,
                        w2.x, w2.y, w2.z, w2.w,
                        w3.x, w3.y, w3.z, w3.w};
        // even- and odd-aligned f16 pair windows covering xv[0..15]
        h2_t E[8], O[7];
#pragma unroll
        for (int i = 0; i < 8; ++i)
          E[i] = __builtin_amdgcn_cvt_pkrtz(xv[2 * i], xv[2 * i + 1]);
#pragma unroll
        for (int i = 0; i < 7; ++i)
          O[i] = __builtin_amdgcn_cvt_pkrtz(xv[2 * i + 1], xv[2 * i + 2]);
#pragma unroll
        for (int p = 0; p < 8; ++p) {
          const h2_t* P = (p & 1) ? (O + (p >> 1)) : (E + (p >> 1));
          float tail = xv[8 + p];
          // conv + mantissa-tag: zp[k] = (bits(z) & ~7) | k  (v_and_or_b32)
          float zp[8];
#pragma unroll
          for (int k = 0; k < 8; ++k) {
            float a0 = Wt[k] * tail;
            a0 = __builtin_amdgcn_fdot2(Wp[k][3], P[3], a0, false);
            a0 = __builtin_amdgcn_fdot2(Wp[k][2], P[2], a0, false);
            a0 = __builtin_amdgcn_fdot2(Wp[k][1], P[1], a0, false);
            a0 = __builtin_amdgcn_fdot2(Wp[k][0], P[0], a0, false);
            zp[k] = __uint_as_float((__float_as_uint(a0) & 0xFFFFFFF8u) | (unsigned)k);
          }
          // max/min trees via v_max3/v_min3: 4+4 ops (was 7+7)
          float t1 = MAX3F(zp[0], zp[1], zp[2]);
          float t2 = MAX3F(zp[3], zp[4], zp[5]);
          float t3 = MAX3F(zp[6], zp[7], t1);
          float mxp = fmaxf(t2, t3);
          float u1 = MIN3F(zp[0], zp[1], zp[2]);
          float u2 = MIN3F(zp[3], zp[4], zp[5]);
          float u3 = MIN3F(zp[6], zp[7], u1);
          float mnp = fminf(u2, u3);
          // cmx: branchless register binning via exact integer tag compare
          // (v_cmp_eq_u32 + v_cndmask + v_add per bin; no LDS, no alias chain)
          unsigned t = __float_as_uint(mxp) & 7u;
#pragma unroll
          for (int k = 0; k < 8; ++k)
            acc[k] += (t == (unsigned)k) ? mxp : 0.f;
          // cmn: packed-byte histogram in a u64 register
          unsigned mnb = __float_as_uint(mnp);
          cmnp += 1ull << ((mnb & 7u) << 3);
        }
        w0 = w2; w1 = w3;
      }
    }
  }

  // ---- flush (registers only, no barrier needed) ----
  {
    int cbase = (DI * 2 + j) * 64;
    // cmx: butterfly-sum each bin over the 8 s-lanes; lane s commits bin s
#pragma unroll
    for (int k = 0; k < 8; ++k) {
#pragma unroll
      for (int off = 1; off < 8; off <<= 1)
        acc[k] += __shfl_xor(acc[k], off);
    }
    float vm = acc[0];
#pragma unroll
    for (int k = 1; k < 8; ++k) vm = (s == k) ? acc[k] : vm;
    atomicAdd(out + ((size_t)b * OUTCH + cbase + g) * 8 + s, vm);

    // cmn: unpack bytes, butterfly over the 8 s-lanes, lane s commits bin s
    int cnts[8];
#pragma unroll
    for (int k = 0; k < 8; ++k) cnts[k] = (int)((cmnp >> (k * 8)) & 0xFFull);
#pragma unroll
    for (int k = 0; k < 8; ++k) {
#pragma unroll
      for (int off = 1; off < 8; off <<= 1)
        cnts[k] += __shfl_xor(cnts[k], off);
    }
    int vn = cnts[0];
#pragma unroll
    for (int k = 1; k < 8; ++k) vn = (s == k) ? cnts[k] : vn;
    atomicAdd(out + ((size_t)b * OUTCH + cbase + 32 + g) * 8 + s, (float)vn);
  }
}

__global__ __launch_bounds__(256, 3) void hydra_fused(
    const float* __restrict__ X, const float* __restrict__ W,
    const int* __restrict__ I, float* __restrict__ out) {
  __shared__ float Xs[XS_FLOATS];
  int u = blockIdx.x;
  int dj = u % 20;            // consecutive blocks interleave (di,j)
  int rest = u / 20;
  int b = rest & 31;
  int chunk = rest >> 5;
  int j = dj & 1;
  switch (dj >> 1) {
    case 0: hydra_body<0>(X, W, I, out, Xs, j, b, chunk); break;
    case 1: hydra_body<1>(X, W, I, out, Xs, j, b, chunk); break;
    case 2: hydra_body<2>(X, W, I, out, Xs, j, b, chunk); break;
    case 3: hydra_body<3>(X, W, I, out, Xs, j, b, chunk); break;
    case 4: hydra_body<4>(X, W, I, out, Xs, j, b, chunk); break;
    case 5: hydra_body<5>(X, W, I, out, Xs, j, b, chunk); break;
    case 6: hydra_body<6>(X, W, I, out, Xs, j, b, chunk); break;
    case 7: hydra_body<7>(X, W, I, out, Xs, j, b, chunk); break;
    case 8: hydra_body<8>(X, W, I, out, Xs, j, b, chunk); break;
    case 9: hydra_body<9>(X, W, I, out, Xs, j, b, chunk); break;
  }
}

__global__ void hydra_relu(float* __restrict__ out, int n) {
  int i = blockIdx.x * 256 + threadIdx.x;
  if (i < n) out[i] = fmaxf(out[i], 0.f);
}

extern "C" void kernel_launch(void* const* d_in, const int* in_sizes, int n_in,
                              void* d_out, int out_size, void* d_ws, size_t ws_size,
                              hipStream_t stream) {
  const float* X = (const float*)d_in[0];
  const float* W = (const float*)d_in[1];
  const int*   I = (const int*)d_in[2];
  float* out = (float*)d_out;

  (void)hipMemsetAsync(d_out, 0, (size_t)out_size * sizeof(float), stream);
  hydra_fused<<<GRID, 256, 0, stream>>>(X, W, I, out);
  hydra_relu<<<(out_size + 255) / 256, 256, 0, stream>>>(out, out_size);
}

// Round 8
// 445.727 us; speedup vs baseline: 1.4678x; 1.1261x over previous
//
#include <hip/hip_runtime.h>

// HydraBackbonePlus: 10 dilations x {X, diffX} x 32 groups, 9-tap grouped dilated
// conv (8 out-ch per group), per-position argmax/argmin over 8 channels,
// histogram-reduced to (32, 1280, 8) with relu.
//
// R18 vs R17 (502 us: reg-binning clean test LOST — +24 VALU/pos (~125us) >
// RMW-chain savings (~44us). R12 Smx-LDS design restored as base.)
// MFMA re-examined from the OUTPUT side: every fragment layout fragments the
// per-position 8-channel argmax across lanes -> post-proc at 16-32 useful
// lanes/wave (vs 64 now), 2-4x more wave-instrs. MFMA closed permanently.
// R18's single change vs R12 (421 us): depth-1 SOFTWARE PIPELINE of ldsum.
//  - iteration i issues iteration i+1's 12 ds_read_b128 at its top; data
//    consumed a full iteration (~575 instrs) later -> LDS latency hidden
//    even at 4 waves/SIMD. Bit-identical numerics.
//  - dead last prefetch reads <=3 floats past tile: XS_FLOATS +8 pad.
// Kept: 8-wide st-loop, v_max3/v_min3, packed-u64 cmn, per-thread Smx slots,
// launch_bounds(256,3) (proven spill-free).

typedef __fp16 h2_t __attribute__((ext_vector_type(2)));

#define NB    32
#define CIN   12
#define SEQ   8192
#define NG    32
#define CPER  6
#define OUTCH 1280
#define XS_FLOATS 7736   // 12 * 644 + 8 pad (dead prefetch overread)
#define GRID  10240      // 20 (di,j) * 32 b * 16 chunks

#define MAX3F(a, b, c) ({ float _r; asm("v_max3_f32 %0, %1, %2, %3" \
    : "=v"(_r) : "v"(a), "v"(b), "v"(c)); _r; })
#define MIN3F(a, b, c) ({ float _r; asm("v_min3_f32 %0, %1, %2, %3" \
    : "=v"(_r) : "v"(a), "v"(b), "v"(c)); _r; })

template <int DI>
__device__ __forceinline__ void hydra_body(
    const float* __restrict__ X, const float* __restrict__ W,
    const int* __restrict__ I, float* __restrict__ out,
    float* Xs, float* Smx, int j, int b, int chunk) {

  constexpr int d   = 1 << DI;
  constexpr int R   = (d < 16) ? d : 16;       // residues per tile row-set
  constexpr int rb  = (DI < 4) ? DI : 4;       // log2(R)
  constexpr int Mm  = SEQ / d;                 // m-extent of a residue
  constexpr int TMc = 512 / R;
  constexpr int TM  = (TMc < Mm) ? TMc : Mm;   // m per tile (DI=9 -> 16)
  constexpr int MC  = Mm / TM;
  constexpr int RC  = d / R;
  constexpr int NR  = (RC * MC) / 16;          // chunks per block: 1 (DI<9), 2 (DI=9)
  constexpr int SR  = TM + 8;                  // row stride (exact halo)
  constexpr int CS  = R * SR + 4;              // channel stride
  constexpr int CL  = (R >= 8) ? TM : (TM * R / 8);  // m per thread per rep
  constexpr int REP = (R == 16) ? 2 : 1;

  const int L = SEQ - j;
  const int tid = threadIdx.x;
  const int g = tid >> 3, s = tid & 7;

  // weights: 8 out-ch x 9 taps -> 4 half2 + 1 f32 tail per channel (40 regs)
  h2_t Wp[8][4];
  float Wt[8];
  {
    const float* wp = W + (size_t)((DI * 2 + j) * 256 + g * 8) * 9;
#pragma unroll
    for (int k = 0; k < 8; ++k) {
#pragma unroll
      for (int t = 0; t < 4; ++t)
        Wp[k][t] = __builtin_amdgcn_cvt_pkrtz(wp[k * 9 + 2 * t], wp[k * 9 + 2 * t + 1]);
      Wt[k] = wp[k * 9 + 8];
    }
  }
  const float* base[CPER];
  {
    const int* ip = I + ((DI * 2 + j) * NG + g) * CPER;
#pragma unroll
    for (int i = 0; i < CPER; ++i) base[i] = Xs + ip[i] * CS;
  }

  // zero the per-thread cmx slots (covered by the staging __syncthreads)
#pragma unroll
  for (int k = 0; k < 8; ++k) Smx[k * 256 + tid] = 0.f;

  // cmn: 8 bins as packed u8 lanes of one u64 (counts <= 64/thread)
  unsigned long long cmnp = 0ull;

  for (int n = 0; n < NR; ++n) {
    const int cidx = chunk + 16 * n;
    const int rc = cidx & (RC - 1);
    const int mc = cidx / RC;
    const int r0 = rc * R;
    const int m0 = mc * TM;

    if (NR > 1 && n) __syncthreads();

    // ---- stage 12-channel tile into LDS, zero-padded; guards hoisted ----
    {
      const float* xb0 = X + (size_t)b * CIN * SEQ;
      if (j == 0) {
        for (int f = tid; f < R * SR; f += 256) {
          int rr = f & (R - 1), mm = f >> rb, mp = m0 + mm - 4;
          int pos = r0 + rr + mp * d;
          bool ok = (mp >= 0) && (pos < L);
          int lo = rr * SR + mm;
          const float* xp = xb0 + pos;
#pragma unroll
          for (int ch = 0; ch < CIN; ++ch) {
            Xs[ch * CS + lo] = ok ? xp[0] : 0.f;
            xp += SEQ;
          }
        }
      } else {
        for (int f = tid; f < R * SR; f += 256) {
          int rr = f & (R - 1), mm = f >> rb, mp = m0 + mm - 4;
          int pos = r0 + rr + mp * d;
          bool ok = (mp >= 0) && (pos < L);
          int lo = rr * SR + mm;
          const float* xp = xb0 + pos;
#pragma unroll
          for (int ch = 0; ch < CIN; ++ch) {
            Xs[ch * CS + lo] = ok ? (xp[1] - xp[0]) : 0.f;
            xp += SEQ;
          }
        }
      }
    }
    __syncthreads();

    // ---- compute: sliding window, dot2 conv, mantissa-tag binning ----
#pragma unroll
    for (int rep = 0; rep < REP; ++rep) {
      int rr = (R == 16) ? (s + (rep << 3)) : (s & (R - 1));
      int mst = (R >= 8) ? 0 : ((s >> rb) * CL);
      int rowoff = rr * SR + mst;

      auto ldsum = [&](int idx) {
        float4 r = *reinterpret_cast<const float4*>(base[0] + idx);
#pragma unroll
        for (int i = 1; i < CPER; ++i) {
          float4 t = *reinterpret_cast<const float4*>(base[i] + idx);
          r.x += t.x; r.y += t.y; r.z += t.z; r.w += t.w;
        }
        return r;
      };

      float4 w0 = ldsum(rowoff);
      float4 w1 = ldsum(rowoff + 4);
      // depth-1 prefetch registers (iteration i holds i+1's loads)
      float4 nw0 = ldsum(rowoff + 8);
      float4 nw1 = ldsum(rowoff + 12);
#pragma unroll 1
      for (int st = 0; st < CL; st += 8) {
        float4 w2 = nw0;
        float4 w3 = nw1;
        // issue next iteration's 12 reads now; consumed a full iter later.
        // Last-iter prefetch is dead (reads <=3 floats past halo, in-array).
        nw0 = ldsum(rowoff + st + 16);
        nw1 = ldsum(rowoff + st + 20);
        float xv[16] = {w0.x, w0.y, w0.z, w0.w,
                        w1.x, w1.y, w1.z, w1.w,
                        w2.x, w2.y, w2.z, w2.w,
                        w3.x, w3.y, w3.z, w3.w};
        // even- and odd-aligned f16 pair windows covering xv[0..15]
        h2_t E[8], O[7];
#pragma unroll
        for (int i = 0; i < 8; ++i)
          E[i] = __builtin_amdgcn_cvt_pkrtz(xv[2 * i], xv[2 * i + 1]);
#pragma unroll
        for (int i = 0; i < 7; ++i)
          O[i] = __builtin_amdgcn_cvt_pkrtz(xv[2 * i + 1], xv[2 * i + 2]);
#pragma unroll
        for (int p = 0; p < 8; ++p) {
          const h2_t* P = (p & 1) ? (O + (p >> 1)) : (E + (p >> 1));
          float tail = xv[8 + p];
          // conv + mantissa-tag: zp[k] = (bits(z) & ~7) | k  (v_and_or_b32)
          float zp[8];
#pragma unroll
          for (int k = 0; k < 8; ++k) {
            float a0 = Wt[k] * tail;
            a0 = __builtin_amdgcn_fdot2(Wp[k][3], P[3], a0, false);
            a0 = __builtin_amdgcn_fdot2(Wp[k][2], P[2], a0, false);
            a0 = __builtin_amdgcn_fdot2(Wp[k][1], P[1], a0, false);
            a0 = __builtin_amdgcn_fdot2(Wp[k][0], P[0], a0, false);
            zp[k] = __uint_as_float((__float_as_uint(a0) & 0xFFFFFFF8u) | (unsigned)k);
          }
          // max/min trees via v_max3/v_min3: 4+4 ops (was 7+7)
          float t1 = MAX3F(zp[0], zp[1], zp[2]);
          float t2 = MAX3F(zp[3], zp[4], zp[5]);
          float t3 = MAX3F(zp[6], zp[7], t1);
          float mxp = fmaxf(t2, t3);
          float u1 = MIN3F(zp[0], zp[1], zp[2]);
          float u2 = MIN3F(zp[3], zp[4], zp[5]);
          float u3 = MIN3F(zp[6], zp[7], u1);
          float mnp = fminf(u2, u3);
          // cmx: contention-free per-thread LDS slot RMW (no atomic, plain
          // ds_read+add+ds_write; compiler pipelines 8 independent slots)
          unsigned mxb = __float_as_uint(mxp);
          Smx[((mxb & 7u) << 8) + tid] += mxp;   // tagged val: <=8 ulp bias
          // cmn: packed-byte histogram in a u64 register
          unsigned mnb = __float_as_uint(mnp);
          cmnp += 1ull << ((mnb & 7u) << 3);
        }
        w0 = w2; w1 = w3;
      }
    }
  }

  __syncthreads();

  // ---- flush ----
  {
    int cbase = (DI * 2 + j) * 64;
    // cmx: thread (g,s) sums bin=s over its 8 member threads
    float sum = 0.f;
#pragma unroll
    for (int s2 = 0; s2 < 8; ++s2) sum += Smx[(s << 8) + (g << 3) + s2];
    atomicAdd(out + ((size_t)b * OUTCH + cbase + g) * 8 + s, sum);

    // cmn: unpack bytes, butterfly over the 8 s-lanes, lane s commits bin s
    int cnts[8];
#pragma unroll
    for (int k = 0; k < 8; ++k) cnts[k] = (int)((cmnp >> (k * 8)) & 0xFFull);
#pragma unroll
    for (int k = 0; k < 8; ++k) {
#pragma unroll
      for (int off = 1; off < 8; off <<= 1)
        cnts[k] += __shfl_xor(cnts[k], off);
    }
    int vn = cnts[0];
#pragma unroll
    for (int k = 1; k < 8; ++k) vn = (s == k) ? cnts[k] : vn;
    atomicAdd(out + ((size_t)b * OUTCH + cbase + 32 + g) * 8 + s, (float)vn);
  }
}

__global__ __launch_bounds__(256, 3) void hydra_fused(
    const float* __restrict__ X, const float* __restrict__ W,
    const int* __restrict__ I, float* __restrict__ out) {
  __shared__ float Xs[XS_FLOATS];
  __shared__ float Smx[2048];   // 8 bins x 256 threads
  int u = blockIdx.x;
  int dj = u % 20;            // consecutive blocks interleave (di,j)
  int rest = u / 20;
  int b = rest & 31;
  int chunk = rest >> 5;
  int j = dj & 1;
  switch (dj >> 1) {
    case 0: hydra_body<0>(X, W, I, out, Xs, Smx, j, b, chunk); break;
    case 1: hydra_body<1>(X, W, I, out, Xs, Smx, j, b, chunk); break;
    case 2: hydra_body<2>(X, W, I, out, Xs, Smx, j, b, chunk); break;
    case 3: hydra_body<3>(X, W, I, out, Xs, Smx, j, b, chunk); break;
    case 4: hydra_body<4>(X, W, I, out, Xs, Smx, j, b, chunk); break;
    case 5: hydra_body<5>(X, W, I, out, Xs, Smx, j, b, chunk); break;
    case 6: hydra_body<6>(X, W, I, out, Xs, Smx, j, b, chunk); break;
    case 7: hydra_body<7>(X, W, I, out, Xs, Smx, j, b, chunk); break;
    case 8: hydra_body<8>(X, W, I, out, Xs, Smx, j, b, chunk); break;
    case 9: hydra_body<9>(X, W, I, out, Xs, Smx, j, b, chunk); break;
  }
}

__global__ void hydra_relu(float* __restrict__ out, int n) {
  int i = blockIdx.x * 256 + threadIdx.x;
  if (i < n) out[i] = fmaxf(out[i], 0.f);
}

extern "C" void kernel_launch(void* const* d_in, const int* in_sizes, int n_in,
                              void* d_out, int out_size, void* d_ws, size_t ws_size,
                              hipStream_t stream) {
  const float* X = (const float*)d_in[0];
  const float* W = (const float*)d_in[1];
  const int*   I = (const int*)d_in[2];
  float* out = (float*)d_out;

  (void)hipMemsetAsync(d_out, 0, (size_t)out_size * sizeof(float), stream);
  hydra_fused<<<GRID, 256, 0, stream>>>(X, W, I, out);
  hydra_relu<<<(out_size + 255) / 256, 256, 0, stream>>>(out, out_size);
}

// Round 9
// 421.568 us; speedup vs baseline: 1.5519x; 1.0573x over previous
//
#include <hip/hip_runtime.h>

// HydraBackbonePlus: 10 dilations x {X, diffX} x 32 groups, 9-tap grouped dilated
// conv (8 out-ch per group), per-position argmax/argmin over 8 channels,
// histogram-reduced to (32, 1280, 8) with relu.
//
// R19 vs R18 (446 us FAIL: prefetch -> +20 VGPR partial spill (WRITE 60MB) +
// dead-read conflicts. Reverted to R12 base, 421 us).
// Conflict localization: R13 null (R>=8 stride change, -0.5%) + R15 (ldsum
// count halved -> conflicts halved) => conflicts live in DI0-2 ldsum: for R<8,
// chunk offset mst=(s>>rb)*64 floats = 256B = 0 mod 128B -> all 8 s-lanes of a
// g start on the SAME bank quad (DI0 8-way clustered, DI1 4-way, DI2 2-way).
// R19 single change: SEGMENTED chunk layout for R<8 (bit-identical):
//  - each 64-pos chunk stored as a 76-float segment (64 + 8 duplicated halo
//    + 4 pad); seg stride 76 = 12 mod 32 -> s-lane starts all-distinct banks
//    (DI0: 12s; DI1: 16rr+12c; DI2: 24rr+12c — verified distinct mod 32)
//  - CS: DI0-2 -> 612 (<= 644 max, LDS size unchanged); DI>=3 untouched
// Kept: 8-wide st-loop, v_max3/v_min3, packed-u64 cmn, per-thread Smx slots,
// launch_bounds(256,3).

typedef __fp16 h2_t __attribute__((ext_vector_type(2)));

#define NB    32
#define CIN   12
#define SEQ   8192
#define NG    32
#define CPER  6
#define OUTCH 1280
#define XS_FLOATS 7728   // 12 * 644 = max over DI of CIN*CS
#define GRID  10240      // 20 (di,j) * 32 b * 16 chunks

#define MAX3F(a, b, c) ({ float _r; asm("v_max3_f32 %0, %1, %2, %3" \
    : "=v"(_r) : "v"(a), "v"(b), "v"(c)); _r; })
#define MIN3F(a, b, c) ({ float _r; asm("v_min3_f32 %0, %1, %2, %3" \
    : "=v"(_r) : "v"(a), "v"(b), "v"(c)); _r; })

template <int DI>
__device__ __forceinline__ void hydra_body(
    const float* __restrict__ X, const float* __restrict__ W,
    const int* __restrict__ I, float* __restrict__ out,
    float* Xs, float* Smx, int j, int b, int chunk) {

  constexpr int d   = 1 << DI;
  constexpr int R   = (d < 16) ? d : 16;       // residues per tile row-set
  constexpr int rb  = (DI < 4) ? DI : 4;       // log2(R)
  constexpr int Mm  = SEQ / d;                 // m-extent of a residue
  constexpr int TMc = 512 / R;
  constexpr int TM  = (TMc < Mm) ? TMc : Mm;   // m per tile (DI=9 -> 16)
  constexpr int MC  = Mm / TM;
  constexpr int RC  = d / R;
  constexpr int NR  = (RC * MC) / 16;          // chunks per block: 1 (DI<9), 2 (DI=9)
  // R<8: segmented chunk layout. CPR 64-pos chunks per row, each a SEG=76
  // float segment (64 + 8 duplicated halo + 4 pad; 76 = 12 mod 32 -> s-lanes
  // hit distinct banks). R>=8: original packed row (R13 null: leave alone).
  constexpr int CPR = (R < 8) ? (TM / 64) : 1;
  constexpr int CB  = (R < 8) ? ((TM == 512) ? 3 : (TM == 256) ? 2 : 1) : 0;
  constexpr int SEG = 76;
  constexpr int SR  = (R < 8) ? (CPR * SEG) : (TM + 8);   // row stride
  constexpr int CS  = R * SR + 4;              // channel stride (DI0-2: 612)
  constexpr int CL  = (R >= 8) ? TM : (TM * R / 8);  // m per thread per rep (=64 for R<8)
  constexpr int REP = (R == 16) ? 2 : 1;

  const int L = SEQ - j;
  const int tid = threadIdx.x;
  const int g = tid >> 3, s = tid & 7;

  // weights: 8 out-ch x 9 taps -> 4 half2 + 1 f32 tail per channel (40 regs)
  h2_t Wp[8][4];
  float Wt[8];
  {
    const float* wp = W + (size_t)((DI * 2 + j) * 256 + g * 8) * 9;
#pragma unroll
    for (int k = 0; k < 8; ++k) {
#pragma unroll
      for (int t = 0; t < 4; ++t)
        Wp[k][t] = __builtin_amdgcn_cvt_pkrtz(wp[k * 9 + 2 * t], wp[k * 9 + 2 * t + 1]);
      Wt[k] = wp[k * 9 + 8];
    }
  }
  const float* base[CPER];
  {
    const int* ip = I + ((DI * 2 + j) * NG + g) * CPER;
#pragma unroll
    for (int i = 0; i < CPER; ++i) base[i] = Xs + ip[i] * CS;
  }

  // zero the per-thread cmx slots (covered by the staging __syncthreads)
#pragma unroll
  for (int k = 0; k < 8; ++k) Smx[k * 256 + tid] = 0.f;

  // cmn: 8 bins as packed u8 lanes of one u64 (counts <= 64/thread)
  unsigned long long cmnp = 0ull;

  for (int n = 0; n < NR; ++n) {
    const int cidx = chunk + 16 * n;
    const int rc = cidx & (RC - 1);
    const int mc = cidx / RC;
    const int r0 = rc * R;
    const int m0 = mc * TM;

    if (NR > 1 && n) __syncthreads();

    // ---- stage 12-channel tile into LDS, zero-padded; guards hoisted ----
    {
      const float* xb0 = X + (size_t)b * CIN * SEQ;
      if (R < 8) {
        // segmented: f -> (row rr, chunk c, within); halo duplicated per chunk
        constexpr int NSTG = R * CPR * 72;     // = 576 for DI 0-2
        for (int f = tid; f < NSTG; f += 256) {
          int within = f % 72;
          int q = f / 72;                      // [0, 8)
          int c = q & (CPR - 1);
          int rr = q >> CB;
          int mp = m0 + (c << 6) + within - 4;
          int pos = r0 + rr + mp * d;
          bool ok = (mp >= 0) && (pos < L);
          int lo = rr * SR + c * SEG + within;
          const float* xp = xb0 + pos;
          if (j == 0) {
#pragma unroll
            for (int ch = 0; ch < CIN; ++ch) {
              Xs[ch * CS + lo] = ok ? xp[0] : 0.f;
              xp += SEQ;
            }
          } else {
#pragma unroll
            for (int ch = 0; ch < CIN; ++ch) {
              Xs[ch * CS + lo] = ok ? (xp[1] - xp[0]) : 0.f;
              xp += SEQ;
            }
          }
        }
      } else if (j == 0) {
        for (int f = tid; f < R * SR; f += 256) {
          int rr = f & (R - 1), mm = f >> rb, mp = m0 + mm - 4;
          int pos = r0 + rr + mp * d;
          bool ok = (mp >= 0) && (pos < L);
          int lo = rr * SR + mm;
          const float* xp = xb0 + pos;
#pragma unroll
          for (int ch = 0; ch < CIN; ++ch) {
            Xs[ch * CS + lo] = ok ? xp[0] : 0.f;
            xp += SEQ;
          }
        }
      } else {
        for (int f = tid; f < R * SR; f += 256) {
          int rr = f & (R - 1), mm = f >> rb, mp = m0 + mm - 4;
          int pos = r0 + rr + mp * d;
          bool ok = (mp >= 0) && (pos < L);
          int lo = rr * SR + mm;
          const float* xp = xb0 + pos;
#pragma unroll
          for (int ch = 0; ch < CIN; ++ch) {
            Xs[ch * CS + lo] = ok ? (xp[1] - xp[0]) : 0.f;
            xp += SEQ;
          }
        }
      }
    }
    __syncthreads();

    // ---- compute: sliding window, dot2 conv, mantissa-tag binning ----
#pragma unroll
    for (int rep = 0; rep < REP; ++rep) {
      int rr = (R == 16) ? (s + (rep << 3)) : (s & (R - 1));
      int rowoff = (R < 8) ? (rr * SR + (s >> rb) * SEG)   // segment start
                           : (rr * SR);

      auto ldsum = [&](int idx) {
        float4 r = *reinterpret_cast<const float4*>(base[0] + idx);
#pragma unroll
        for (int i = 1; i < CPER; ++i) {
          float4 t = *reinterpret_cast<const float4*>(base[i] + idx);
          r.x += t.x; r.y += t.y; r.z += t.z; r.w += t.w;
        }
        return r;
      };

      float4 w0 = ldsum(rowoff);
      float4 w1 = ldsum(rowoff + 4);
#pragma unroll 1
      for (int st = 0; st < CL; st += 8) {
        float4 w2 = ldsum(rowoff + st + 8);
        float4 w3 = ldsum(rowoff + st + 12);
        float xv[16] = {w0.x, w0.y, w0.z, w0.w,
                        w1.x, w1.y, w1.z, w1.w,
                        w2.x, w2.y, w2.z, w2.w,
                        w3.x, w3.y, w3.z, w3.w};
        // even- and odd-aligned f16 pair windows covering xv[0..15]
        h2_t E[8], O[7];
#pragma unroll
        for (int i = 0; i < 8; ++i)
          E[i] = __builtin_amdgcn_cvt_pkrtz(xv[2 * i], xv[2 * i + 1]);
#pragma unroll
        for (int i = 0; i < 7; ++i)
          O[i] = __builtin_amdgcn_cvt_pkrtz(xv[2 * i + 1], xv[2 * i + 2]);
#pragma unroll
        for (int p = 0; p < 8; ++p) {
          const h2_t* P = (p & 1) ? (O + (p >> 1)) : (E + (p >> 1));
          float tail = xv[8 + p];
          // conv + mantissa-tag: zp[k] = (bits(z) & ~7) | k  (v_and_or_b32)
          float zp[8];
#pragma unroll
          for (int k = 0; k < 8; ++k) {
            float a0 = Wt[k] * tail;
            a0 = __builtin_amdgcn_fdot2(Wp[k][3], P[3], a0, false);
            a0 = __builtin_amdgcn_fdot2(Wp[k][2], P[2], a0, false);
            a0 = __builtin_amdgcn_fdot2(Wp[k][1], P[1], a0, false);
            a0 = __builtin_amdgcn_fdot2(Wp[k][0], P[0], a0, false);
            zp[k] = __uint_as_float((__float_as_uint(a0) & 0xFFFFFFF8u) | (unsigned)k);
          }
          // max/min trees via v_max3/v_min3: 4+4 ops (was 7+7)
          float t1 = MAX3F(zp[0], zp[1], zp[2]);
          float t2 = MAX3F(zp[3], zp[4], zp[5]);
          float t3 = MAX3F(zp[6], zp[7], t1);
          float mxp = fmaxf(t2, t3);
          float u1 = MIN3F(zp[0], zp[1], zp[2]);
          float u2 = MIN3F(zp[3], zp[4], zp[5]);
          float u3 = MIN3F(zp[6], zp[7], u1);
          float mnp = fminf(u2, u3);
          // cmx: contention-free per-thread LDS slot RMW (no atomic, plain
          // ds_read+add+ds_write; compiler pipelines 8 independent slots)
          unsigned mxb = __float_as_uint(mxp);
          Smx[((mxb & 7u) << 8) + tid] += mxp;   // tagged val: <=8 ulp bias
          // cmn: packed-byte histogram in a u64 register
          unsigned mnb = __float_as_uint(mnp);
          cmnp += 1ull << ((mnb & 7u) << 3);
        }
        w0 = w2; w1 = w3;
      }
    }
  }

  __syncthreads();

  // ---- flush ----
  {
    int cbase = (DI * 2 + j) * 64;
    // cmx: thread (g,s) sums bin=s over its 8 member threads
    float sum = 0.f;
#pragma unroll
    for (int s2 = 0; s2 < 8; ++s2) sum += Smx[(s << 8) + (g << 3) + s2];
    atomicAdd(out + ((size_t)b * OUTCH + cbase + g) * 8 + s, sum);

    // cmn: unpack bytes, butterfly over the 8 s-lanes, lane s commits bin s
    int cnts[8];
#pragma unroll
    for (int k = 0; k < 8; ++k) cnts[k] = (int)((cmnp >> (k * 8)) & 0xFFull);
#pragma unroll
    for (int k = 0; k < 8; ++k) {
#pragma unroll
      for (int off = 1; off < 8; off <<= 1)
        cnts[k] += __shfl_xor(cnts[k], off);
    }
    int vn = cnts[0];
#pragma unroll
    for (int k = 1; k < 8; ++k) vn = (s == k) ? cnts[k] : vn;
    atomicAdd(out + ((size_t)b * OUTCH + cbase + 32 + g) * 8 + s, (float)vn);
  }
}

__global__ __launch_bounds__(256, 3) void hydra_fused(
    const float* __restrict__ X, const float* __restrict__ W,
    const int* __restrict__ I, float* __restrict__ out) {
  __shared__ float Xs[XS_FLOATS];
  __shared__ float Smx[2048];   // 8 bins x 256 threads
  int u = blockIdx.x;
  int dj = u % 20;            // consecutive blocks interleave (di,j)
  int rest = u / 20;
  int b = rest & 31;
  int chunk = rest >> 5;
  int j = dj & 1;
  switch (dj >> 1) {
    case 0: hydra_body<0>(X, W, I, out, Xs, Smx, j, b, chunk); break;
    case 1: hydra_body<1>(X, W, I, out, Xs, Smx, j, b, chunk); break;
    case 2: hydra_body<2>(X, W, I, out, Xs, Smx, j, b, chunk); break;
    case 3: hydra_body<3>(X, W, I, out, Xs, Smx, j, b, chunk); break;
    case 4: hydra_body<4>(X, W, I, out, Xs, Smx, j, b, chunk); break;
    case 5: hydra_body<5>(X, W, I, out, Xs, Smx, j, b, chunk); break;
    case 6: hydra_body<6>(X, W, I, out, Xs, Smx, j, b, chunk); break;
    case 7: hydra_body<7>(X, W, I, out, Xs, Smx, j, b, chunk); break;
    case 8: hydra_body<8>(X, W, I, out, Xs, Smx, j, b, chunk); break;
    case 9: hydra_body<9>(X, W, I, out, Xs, Smx, j, b, chunk); break;
  }
}

__global__ void hydra_relu(float* __restrict__ out, int n) {
  int i = blockIdx.x * 256 + threadIdx.x;
  if (i < n) out[i] = fmaxf(out[i], 0.f);
}

extern "C" void kernel_launch(void* const* d_in, const int* in_sizes, int n_in,
                              void* d_out, int out_size, void* d_ws, size_t ws_size,
                              hipStream_t stream) {
  const float* X = (const float*)d_in[0];
  const float* W = (const float*)d_in[1];
  const int*   I = (const int*)d_in[2];
  float* out = (float*)d_out;

  (void)hipMemsetAsync(d_out, 0, (size_t)out_size * sizeof(float), stream);
  hydra_fused<<<GRID, 256, 0, stream>>>(X, W, I, out);
  hydra_relu<<<(out_size + 255) / 256, 256, 0, stream>>>(out, out_size);
}